// Round 1
// baseline (1092.806 us; speedup 1.0000x reference)
//
#include <hip/hip_runtime.h>
#include <hip/hip_bf16.h>
#include <stdint.h>

// ---------------------------------------------------------------------------
// WindowedStructCmapCATT on MI355X (gfx950)
// Full pipeline: proj GEMM -> 2x self-MHA -> 2x cross-MHA -> per-bin h GEMMs
// -> cm = h1.h2^T (f32, straight into d_out) -> in-place bin smoothing + cm1
// -> integral-image box sums -> logistic head.
// All matmuls: f16 MFMA (mfma_f32_16x16x32_f16), 128x128 tiles, 4 waves,
// global_load_lds width-16 staging (m97 structure).
// Workspace: ~151 MB (phase-overlaid union region).
// ---------------------------------------------------------------------------

using f16 = _Float16;
typedef _Float16 hfrag __attribute__((ext_vector_type(8)));
typedef float floatx4 __attribute__((ext_vector_type(4)));

#define DEVI __device__ __forceinline__

DEVI float fast_tanh(float x) {
  float a = fabsf(x);
  float e = __expf(2.0f * a);
  float t = 1.0f - 2.0f / (e + 1.0f);
  return x < 0.0f ? -t : t;
}

DEVI void async16(const f16* g, f16* l) {
  __builtin_amdgcn_global_load_lds((__attribute__((address_space(1))) void*)g,
                                   (__attribute__((address_space(3))) void*)l,
                                   16, 0, 0);
}

// ---------------------------------------------------------------------------
// Generic NT GEMM: C[m][n] = scale * sum_k A[m][k]*B[n][k] (+bias) (+res) ...
// A: MxK row-major f16 (lda), B: NxK row-major f16 (ldb).
// Batched over grid.z: z -> (zb = z/zdiv, zh = z%zdiv), per-operand strides.
// ---------------------------------------------------------------------------
struct GA {
  const f16* A; const f16* B;
  f16* Cb; float* Cf; const float* Res; const float* bias;
  long sAb, sAh, sBb, sBh, sCb, sCh;
  int lda, ldb, ldc, K, zdiv;
  float scale;
};

enum { FB_BIAS = 1, FB_RES = 2, FB_OUTF32 = 4, FB_OUTBF16 = 8, FB_TANH = 16, FB_SCALE = 32 };

template <int BM, int BN, int WM, int WN, int FLAGS>
__global__ __launch_bounds__(256) void gemm_nt(GA a) {
  constexpr int MW = BM / WM, NWv = BN / WN;
  constexpr int NWAVES = MW * NWv;            // always 4 here
  constexpr int MI = WM / 16, NI = WN / 16;
  constexpr int CA_ = (4 * BM) / (64 * NWAVES);
  constexpr int CB_ = (4 * BN) / (64 * NWAVES);

  const int lane = threadIdx.x & 63;
  const int w = threadIdx.x >> 6;
  const int wm = w % MW, wn = w / MW;

  const int z = blockIdx.z;
  const int zb = z / a.zdiv, zh = z % a.zdiv;
  const f16* Ap = a.A + zb * a.sAb + zh * a.sAh + (long)blockIdx.x * BM * a.lda;
  const f16* Bp = a.B + zb * a.sBb + zh * a.sBh + (long)blockIdx.y * BN * a.ldb;

  __shared__ __attribute__((aligned(16))) f16 sA[BM * 32];
  __shared__ __attribute__((aligned(16))) f16 sB[BN * 32];

  floatx4 acc[MI][NI] = {};

  for (int k0 = 0; k0 < a.K; k0 += 32) {
    __syncthreads();
#pragma unroll
    for (int c = 0; c < CA_; ++c) {
      int s = (w * CA_ + c) * 64 + lane;
      int g = s / BM, r = s - g * BM;
      async16(Ap + (long)r * a.lda + (k0 + g * 8), &sA[s * 8]);
    }
#pragma unroll
    for (int c = 0; c < CB_; ++c) {
      int s = (w * CB_ + c) * 64 + lane;
      int g = s / BN, r = s - g * BN;
      async16(Bp + (long)r * a.ldb + (k0 + g * 8), &sB[s * 8]);
    }
    __syncthreads();  // waits vmcnt(0): global_load_lds complete

    hfrag af[MI], bfr[NI];
#pragma unroll
    for (int i = 0; i < MI; ++i)
      af[i] = *(const hfrag*)&sA[((lane >> 4) * BM + wm * WM + i * 16 + (lane & 15)) * 8];
#pragma unroll
    for (int j = 0; j < NI; ++j)
      bfr[j] = *(const hfrag*)&sB[((lane >> 4) * BN + wn * WN + j * 16 + (lane & 15)) * 8];
#pragma unroll
    for (int i = 0; i < MI; ++i)
#pragma unroll
      for (int j = 0; j < NI; ++j)
        acc[i][j] = __builtin_amdgcn_mfma_f32_16x16x32_f16(af[i], bfr[j], acc[i][j], 0, 0, 0);
  }

  // Epilogue. C/D layout: row=(lane>>4)*4+r, col=lane&15 (m89-verified).
  const long zofsC = zb * a.sCb + zh * a.sCh;
  const int r0 = (lane >> 4) * 4, c0 = lane & 15;
#pragma unroll
  for (int i = 0; i < MI; ++i) {
#pragma unroll
    for (int j = 0; j < NI; ++j) {
      int coll = wn * WN + j * 16 + c0;
      int gc = blockIdx.y * BN + coll;
#pragma unroll
      for (int r = 0; r < 4; ++r) {
        long row = (long)blockIdx.x * BM + wm * WM + i * 16 + r0 + r;
        float v = acc[i][j][r];
        if constexpr ((FLAGS & FB_SCALE) != 0) v *= a.scale;
        if constexpr ((FLAGS & FB_BIAS) != 0) v += a.bias[gc];
        long idx = row * a.ldc + gc + zofsC;
        if constexpr ((FLAGS & FB_RES) != 0) v += a.Res[idx];
        if constexpr ((FLAGS & FB_OUTF32) != 0) a.Cf[idx] = v;
        if constexpr ((FLAGS & FB_TANH) != 0) v = fast_tanh(v);
        if constexpr ((FLAGS & FB_OUTBF16) != 0) a.Cb[idx] = (f16)v;
      }
    }
  }
}

// ------------------------------ aux kernels --------------------------------

__global__ void k_cvt(const float* __restrict__ s, unsigned short* __restrict__ d, int n) {
  int i = (blockIdx.x * 256 + threadIdx.x) * 4;
  if (i >= n) return;
  float4 v = *(const float4*)(s + i);
  union { f16 h; unsigned short u; } c0, c1, c2, c3;
  c0.h = (f16)v.x; c1.h = (f16)v.y; c2.h = (f16)v.z; c3.h = (f16)v.w;
  ushort4 o; o.x = c0.u; o.y = c1.u; o.z = c2.u; o.w = c3.u;
  *(ushort4*)(d + i) = o;
}

// Wbins[n][d][k] (f32, 512x256) -> O[n][k][d] (f16, 256x512)
__global__ void k_binsT(const float* __restrict__ W, f16* __restrict__ O) {
  __shared__ float t[32][33];
  int n = blockIdx.z;
  int k0 = blockIdx.x * 32, d0 = blockIdx.y * 32;
  int tx = threadIdx.x & 31, ty = threadIdx.x >> 5;
  const float* Wn = W + (long)n * 131072;
#pragma unroll
  for (int rr = 0; rr < 32; rr += 8)
    t[ty + rr][tx] = Wn[(long)(d0 + ty + rr) * 256 + k0 + tx];
  __syncthreads();
  f16* On = O + (long)n * 131072;
#pragma unroll
  for (int rr = 0; rr < 32; rr += 8)
    On[(long)(k0 + ty + rr) * 512 + d0 + tx] = (f16)t[tx][ty + rr];
}

// qkv[(b*512+l)*1536 + 1024 + h*64 + d] -> vT[((b*8+h)*64 + d)*512 + l]
__global__ void k_vtrans(const unsigned short* __restrict__ qkv, unsigned short* __restrict__ vT) {
  __shared__ unsigned short t[32][33];
  int z = blockIdx.z, b = z >> 3, h = z & 7;
  int l0 = blockIdx.x * 32, d0 = blockIdx.y * 32;
  int tx = threadIdx.x & 31, ty = threadIdx.x >> 5;
  const unsigned short* src = qkv + (long)b * 512 * 1536 + 1024 + h * 64;
#pragma unroll
  for (int rr = 0; rr < 32; rr += 8)
    t[ty + rr][tx] = src[(long)(l0 + ty + rr) * 1536 + d0 + tx];
  __syncthreads();
  unsigned short* dst = vT + (long)z * 64 * 512;
#pragma unroll
  for (int rr = 0; rr < 32; rr += 8)
    dst[(long)(d0 + ty + rr) * 512 + l0 + tx] = t[tx][ty + rr];
}

// in-place softmax over rows of 512 f16; one wave per row.
__global__ void k_softmax(unsigned short* __restrict__ S) {
  int row = blockIdx.x * 4 + (threadIdx.x >> 6);
  int lane = threadIdx.x & 63;
  unsigned short* p = S + (long)row * 512 + lane * 8;
  union { uint4 v; f16 h[8]; } cv;
  cv.v = *(const uint4*)p;
  float f[8];
#pragma unroll
  for (int i = 0; i < 8; ++i) f[i] = (float)cv.h[i];
  float m = f[0];
#pragma unroll
  for (int i = 1; i < 8; ++i) m = fmaxf(m, f[i]);
#pragma unroll
  for (int o = 32; o > 0; o >>= 1) m = fmaxf(m, __shfl_xor(m, o));
  float sum = 0.f;
#pragma unroll
  for (int i = 0; i < 8; ++i) { f[i] = __expf(f[i] - m); sum += f[i]; }
#pragma unroll
  for (int o = 32; o > 0; o >>= 1) sum += __shfl_xor(sum, o);
  float inv = 1.0f / sum;
#pragma unroll
  for (int i = 0; i < 8; ++i) cv.h[i] = (f16)(f[i] * inv);
  *(uint4*)p = cv.v;
}

// In-place bin smoothing on cm (d_out, f32) + agg-weighted tanh -> cm1.
// grid (512=i, 8=b), 256 thr, thread owns (i, j..j+1) for ALL 25 bins.
__global__ void k_smooth(float* __restrict__ cm, const float* __restrict__ sm,
                         const float* __restrict__ agg, float* __restrict__ cm1) {
  int i = blockIdx.x, b = blockIdx.y;
  int j = threadIdx.x * 2;
  float sw[5];
#pragma unroll
  for (int k = 0; k < 5; ++k) sw[k] = sm[k];
  float r0[25], r1[25];
  float* base = cm + (long)b * 25 * 262144 + (long)i * 512 + j;
#pragma unroll
  for (int n = 0; n < 25; ++n) {
    float2 t = *(const float2*)(base + (long)n * 262144);
    r0[n] = t.x; r1[n] = t.y;
  }
  float a0 = 0.f, a1 = 0.f;
#pragma unroll
  for (int n = 0; n < 25; ++n) {
    float t0 = 0.f, t1 = 0.f;
#pragma unroll
    for (int k = 0; k < 5; ++k) {
      int mi = n + k - 2;
      if (mi >= 0 && mi < 25) { t0 += sw[k] * r0[mi]; t1 += sw[k] * r1[mi]; }
    }
    float2 o2; o2.x = t0; o2.y = t1;
    *(float2*)(base + (long)n * 262144) = o2;
    float ag = agg[n];
    a0 += ag * t0; a1 += ag * t1;
  }
  float2 c2; c2.x = fast_tanh(a0); c2.y = fast_tanh(a1);
  *(float2*)(cm1 + ((long)b * 512 + i) * 512 + j) = c2;
}

// rowpre[b][a][j] = sum_{c=j}^{j+502} cm1[b][a][c], j=0..9. One wave per row.
__global__ void k_rowpre(const float* __restrict__ cm1, float* __restrict__ rp) {
  int r = blockIdx.x * 4 + (threadIdx.x >> 6);
  int lane = threadIdx.x & 63;
  const float* row = cm1 + (long)r * 512;
  float4 v0 = *(const float4*)(row + lane * 8);
  float4 v1 = *(const float4*)(row + lane * 8 + 4);
  float t = ((v0.x + v0.y) + (v0.z + v0.w)) + ((v1.x + v1.y) + (v1.z + v1.w));
#pragma unroll
  for (int o = 32; o > 0; o >>= 1) t += __shfl_xor(t, o);
  float r8 = __shfl(v0.x, 1);
  float r503 = __shfl(v1.w, 62);
  float q0 = __shfl(v0.x, 63), q1 = __shfl(v0.y, 63), q2 = __shfl(v0.z, 63), q3 = __shfl(v0.w, 63);
  float q4 = __shfl(v1.x, 63), q5 = __shfl(v1.y, 63), q6 = __shfl(v1.z, 63), q7 = __shfl(v1.w, 63);
  if (lane == 0) {
    float first[9] = {v0.x, v0.y, v0.z, v0.w, v1.x, v1.y, v1.z, v1.w, r8};
    float last[9] = {r503, q0, q1, q2, q3, q4, q5, q6, q7};  // rows 503..511
    float suf[10]; suf[0] = 0.f;
#pragma unroll
    for (int s2 = 1; s2 <= 9; ++s2) suf[s2] = suf[s2 - 1] + last[9 - s2];
    float pre = 0.f;
#pragma unroll
    for (int jj = 0; jj < 10; ++jj) {
      rp[(long)r * 10 + jj] = t - pre - suf[9 - jj];
      pre += first[jj];
    }
  }
}

// wsum[b][i][j] = sum_{a=i}^{i+502} rowpre[b][a][j]; block per (b,j).
__global__ void k_wsum(const float* __restrict__ rp, float* __restrict__ wst) {
  int b = blockIdx.x / 10, j = blockIdx.x % 10;
  int t = threadIdx.x;
  const float* base = rp + (long)b * 5120 + j;
  float v = base[(long)t * 10] + base[(long)(t + 256) * 10];
  __shared__ float sh[256];
  sh[t] = v;
  __syncthreads();
  for (int s = 128; s > 0; s >>= 1) {
    if (t < s) sh[t] += sh[t + s];
    __syncthreads();
  }
  if (t == 0) {
    float total = sh[0];
    float suf[10]; suf[0] = 0.f;
    for (int s2 = 1; s2 <= 9; ++s2) suf[s2] = suf[s2 - 1] + base[(long)(512 - s2) * 10];
    float pre = 0.f;
    for (int i2 = 0; i2 < 10; ++i2) {
      wst[b * 100 + i2 * 10 + j] = total - pre - suf[9 - i2];
      pre += base[(long)i2 * 10];
    }
  }
}

__global__ void k_pp(const float* __restrict__ wst, const float* __restrict__ Lmat,
                     const float* __restrict__ biasp, float* __restrict__ out) {
  int b = threadIdx.x;
  if (b < 8) {
    float acc = biasp[0];
    for (int p = 0; p < 100; ++p) acc += fast_tanh(wst[b * 100 + p]) * Lmat[p];
    out[b] = 1.0f / (1.0f + __expf(-acc));
  }
}

// ------------------------------ host launcher ------------------------------

extern "C" void kernel_launch(void* const* d_in, const int* in_sizes, int n_in,
                              void* d_out, int out_size, void* d_ws, size_t ws_size,
                              hipStream_t stream) {
  (void)in_sizes; (void)n_in; (void)out_size; (void)ws_size;
  const float* x1 = (const float*)d_in[0];
  const float* x2 = (const float*)d_in[1];
  const float* proj_w = (const float*)d_in[2];
  const float* proj_b = (const float*)d_in[3];
  const float* mha_in_w = (const float*)d_in[4];
  const float* mha_in_b = (const float*)d_in[5];
  const float* mha_out_w = (const float*)d_in[6];
  const float* mha_out_b = (const float*)d_in[7];
  const float* ca_in_w = (const float*)d_in[8];
  const float* ca_in_b = (const float*)d_in[9];
  const float* ca_out_w = (const float*)d_in[10];
  const float* ca_out_b = (const float*)d_in[11];
  const float* Wbins = (const float*)d_in[12];
  const float* agg = (const float*)d_in[13];
  const float* Lmat = (const float*)d_in[14];
  const float* biasp = (const float*)d_in[15];
  const float* smooth = (const float*)d_in[16];

  float* out_cm = (float*)d_out;
  float* out_pp = out_cm + 52428800L;

  char* w = (char*)d_ws;
  size_t o = 0;
  auto take = [&](size_t bytes) {
    void* p = w + o;
    o += bytes;
    o = (o + 255) & ~(size_t)255;
    return p;
  };
  f16* wbProj = (f16*)take(1048576);
  f16* wbMhaIn = (f16*)take(1572864);
  f16* wbMhaOut = (f16*)take(524288);
  f16* wbCaIn = (f16*)take(1572864);
  f16* wbCaOut = (f16*)take(524288);
  f16* wbBins = (f16*)take(6553600);
  float* xf1 = (float*)take(8388608);
  float* xf2 = (float*)take(8388608);
  f16* xb1 = (f16*)take(4194304);
  f16* xb2 = (f16*)take(4194304);
  float* cm1 = (float*)take(8388608);
  float* rowpre = (float*)take(163840);
  float* wst = (float*)take(3328);
  char* U = w + o;  // union region: phase1 attention (~84MB) / phase2 h1+h2 (~100MB)
  f16* xin1b = (f16*)(U);
  f16* xin2b = (f16*)(U + 8388608);
  f16* qkv1 = (f16*)(U + 16777216);
  f16* qkv2 = (f16*)(U + 29360128);
  f16* vT = (f16*)(U + 41943040);
  f16* S = (f16*)(U + 46137344);
  f16* ao = (f16*)(U + 79691776);
  f16* h1 = (f16*)(U);
  f16* h2 = (f16*)(U + 52428800);
  // total ws usage: ~151 MB

  // --- weight / input conversions to f16 ---
  k_cvt<<<512, 256, 0, stream>>>(proj_w, (unsigned short*)wbProj, 524288);
  k_cvt<<<768, 256, 0, stream>>>(mha_in_w, (unsigned short*)wbMhaIn, 786432);
  k_cvt<<<256, 256, 0, stream>>>(mha_out_w, (unsigned short*)wbMhaOut, 262144);
  k_cvt<<<768, 256, 0, stream>>>(ca_in_w, (unsigned short*)wbCaIn, 786432);
  k_cvt<<<256, 256, 0, stream>>>(ca_out_w, (unsigned short*)wbCaOut, 262144);
  k_cvt<<<4096, 256, 0, stream>>>(x1, (unsigned short*)xin1b, 4194304);
  k_cvt<<<4096, 256, 0, stream>>>(x2, (unsigned short*)xin2b, 4194304);
  k_binsT<<<dim3(8, 16, 25), 256, 0, stream>>>(Wbins, wbBins);

  // --- projection: xf = xin @ proj_w^T + b ; xb = f16(xf) ---
  {
    GA g{}; g.A = xin1b; g.lda = 1024; g.B = wbProj; g.ldb = 1024; g.bias = proj_b;
    g.Cf = xf1; g.Cb = xb1; g.ldc = 512; g.K = 1024; g.zdiv = 1; g.scale = 1.f;
    gemm_nt<128, 128, 64, 64, FB_BIAS | FB_OUTF32 | FB_OUTBF16><<<dim3(32, 4, 1), 256, 0, stream>>>(g);
    g.A = xin2b; g.Cf = xf2; g.Cb = xb2;
    gemm_nt<128, 128, 64, 64, FB_BIAS | FB_OUTF32 | FB_OUTBF16><<<dim3(32, 4, 1), 256, 0, stream>>>(g);
  }

  auto attention = [&](f16* qkv, float* xf, f16* xb_out, const f16* w_out,
                       const float* b_out, bool writeF32) {
    k_vtrans<<<dim3(16, 2, 64), 256, 0, stream>>>((const unsigned short*)qkv, (unsigned short*)vT);
    {  // S = softmax-input: Q.K^T / 8, batched over (b,h)
      GA g{}; g.A = qkv; g.lda = 1536; g.sAb = 786432; g.sAh = 64;
      g.B = qkv + 512; g.ldb = 1536; g.sBb = 786432; g.sBh = 64;
      g.Cb = S; g.ldc = 512; g.sCb = 2097152; g.sCh = 262144;
      g.K = 64; g.zdiv = 8; g.scale = 0.125f;
      gemm_nt<128, 128, 64, 64, FB_SCALE | FB_OUTBF16><<<dim3(4, 4, 64), 256, 0, stream>>>(g);
    }
    k_softmax<<<8192, 256, 0, stream>>>((unsigned short*)S);
    {  // ao = P.V  (B = vT slice, NT form)
      GA g{}; g.A = S; g.lda = 512; g.sAb = 2097152; g.sAh = 262144;
      g.B = vT; g.ldb = 512; g.sBb = 262144; g.sBh = 32768;
      g.Cb = ao; g.ldc = 512; g.sCb = 262144; g.sCh = 64;
      g.K = 512; g.zdiv = 8; g.scale = 1.f;
      gemm_nt<128, 64, 64, 32, FB_OUTBF16><<<dim3(4, 1, 64), 256, 0, stream>>>(g);
    }
    {  // out proj + residual (+tanh into xb_out)
      GA g{}; g.A = ao; g.lda = 512; g.B = w_out; g.ldb = 512; g.bias = b_out;
      g.Res = xf; g.Cb = xb_out; g.ldc = 512; g.K = 512; g.zdiv = 1; g.scale = 1.f;
      if (writeF32) {
        g.Cf = xf;
        gemm_nt<128, 128, 64, 64, FB_BIAS | FB_RES | FB_OUTF32 | FB_OUTBF16 | FB_TANH>
            <<<dim3(32, 4, 1), 256, 0, stream>>>(g);
      } else {
        gemm_nt<128, 128, 64, 64, FB_BIAS | FB_RES | FB_OUTBF16 | FB_TANH>
            <<<dim3(32, 4, 1), 256, 0, stream>>>(g);
      }
    }
  };

  // --- self-MHA x1 ---
  {
    GA g{}; g.A = xb1; g.lda = 512; g.B = wbMhaIn; g.ldb = 512; g.bias = mha_in_b;
    g.Cb = qkv1; g.ldc = 1536; g.K = 512; g.zdiv = 1; g.scale = 1.f;
    gemm_nt<128, 128, 64, 64, FB_BIAS | FB_OUTBF16><<<dim3(32, 12, 1), 256, 0, stream>>>(g);
  }
  attention(qkv1, xf1, xb1, wbMhaOut, mha_out_b, true);
  // --- self-MHA x2 ---
  {
    GA g{}; g.A = xb2; g.lda = 512; g.B = wbMhaIn; g.ldb = 512; g.bias = mha_in_b;
    g.Cb = qkv2; g.ldc = 1536; g.K = 512; g.zdiv = 1; g.scale = 1.f;
    gemm_nt<128, 128, 64, 64, FB_BIAS | FB_OUTBF16><<<dim3(32, 12, 1), 256, 0, stream>>>(g);
  }
  attention(qkv2, xf2, xb2, wbMhaOut, mha_out_b, true);

  // --- cross-attention QKV (q from own tanh'd x, kv from the other) ---
  auto ca_qkv = [&](f16* xq, f16* xkv, f16* qkv) {
    GA g{}; g.A = xq; g.lda = 512; g.B = wbCaIn; g.ldb = 512; g.bias = ca_in_b;
    g.Cb = qkv; g.ldc = 1536; g.K = 512; g.zdiv = 1; g.scale = 1.f;
    gemm_nt<128, 128, 64, 64, FB_BIAS | FB_OUTBF16><<<dim3(32, 4, 1), 256, 0, stream>>>(g);
    GA g2{}; g2.A = xkv; g2.lda = 512; g2.B = wbCaIn + 262144; g2.ldb = 512;
    g2.bias = ca_in_b + 512; g2.Cb = qkv + 512; g2.ldc = 1536; g2.K = 512; g2.zdiv = 1; g2.scale = 1.f;
    gemm_nt<128, 128, 64, 64, FB_BIAS | FB_OUTBF16><<<dim3(32, 8, 1), 256, 0, stream>>>(g2);
  };
  ca_qkv(xb1, xb2, qkv1);
  ca_qkv(xb2, xb1, qkv2);
  attention(qkv1, xf1, xb1, wbCaOut, ca_out_b, false);  // xb1 = tanh(x1 + CA)
  attention(qkv2, xf2, xb2, wbCaOut, ca_out_b, false);  // xb2 = tanh(x2 + CA)

  // --- h GEMMs: h[b,n] = tanh(xb[b] @ wbBins[n]^T), z = b*25+n ---
  {
    GA g{}; g.A = xb1; g.lda = 512; g.sAb = 262144; g.sAh = 0;
    g.B = wbBins; g.ldb = 512; g.sBb = 0; g.sBh = 131072;
    g.Cb = h1; g.ldc = 256; g.sCb = 3276800; g.sCh = 131072;
    g.K = 512; g.zdiv = 25; g.scale = 1.f;
    gemm_nt<128, 128, 64, 64, FB_OUTBF16 | FB_TANH><<<dim3(4, 2, 200), 256, 0, stream>>>(g);
    g.A = xb2; g.Cb = h2;
    gemm_nt<128, 128, 64, 64, FB_OUTBF16 | FB_TANH><<<dim3(4, 2, 200), 256, 0, stream>>>(g);
  }

  // --- cm_raw = h1 @ h2^T (f32, straight into d_out) ---
  {
    GA g{}; g.A = h1; g.lda = 256; g.sAb = 131072; g.sAh = 0;
    g.B = h2; g.ldb = 256; g.sBb = 131072; g.sBh = 0;
    g.Cf = out_cm; g.ldc = 512; g.sCb = 262144; g.sCh = 0;
    g.K = 256; g.zdiv = 1; g.scale = 1.f;
    gemm_nt<128, 128, 64, 64, FB_OUTF32><<<dim3(4, 4, 200), 256, 0, stream>>>(g);
  }

  // --- bin smoothing (in-place on d_out) + cm1 = tanh(sum_n agg*cm) ---
  k_smooth<<<dim3(512, 8), 256, 0, stream>>>(out_cm, smooth, agg, cm1);

  // --- integral-image box sums + logistic head ---
  k_rowpre<<<1024, 256, 0, stream>>>(cm1, rowpre);
  k_wsum<<<80, 256, 0, stream>>>(rowpre, wst);
  k_pp<<<1, 64, 0, stream>>>(wst, Lmat, biasp, out_pp);
}

// Round 2
// 806.788 us; speedup vs baseline: 1.3545x; 1.3545x over previous
//
#include <hip/hip_runtime.h>
#include <hip/hip_bf16.h>
#include <stdint.h>

// ---------------------------------------------------------------------------
// WindowedStructCmapCATT on MI355X (gfx950) — Round 2
// Changes vs R1: z-batched GEMMs (x1/x2 pairs + all (b,h) attention), fused
// S-GEMM+softmax kernel, raw cm stored f16 in ws, rowpre fused into smooth,
// fused weight conversions, 128x64 tiles for tall GEMMs. 20 launches total.
// ---------------------------------------------------------------------------

using f16 = _Float16;
typedef _Float16 hfrag __attribute__((ext_vector_type(8)));
typedef _Float16 f16x4 __attribute__((ext_vector_type(4)));
typedef _Float16 f16x2 __attribute__((ext_vector_type(2)));
typedef float floatx4 __attribute__((ext_vector_type(4)));

#define DEVI __device__ __forceinline__

DEVI float fast_tanh(float x) {
  float a = fabsf(x);
  float e = __expf(2.0f * a);
  float t = 1.0f - 2.0f / (e + 1.0f);
  return x < 0.0f ? -t : t;
}

DEVI void async16(const f16* g, f16* l) {
  __builtin_amdgcn_global_load_lds((__attribute__((address_space(1))) void*)g,
                                   (__attribute__((address_space(3))) void*)l,
                                   16, 0, 0);
}

// ---------------------------------------------------------------------------
// Generic NT GEMM: C[m][n] = sum_k A[m][k]*B[n][k] (+bias)(+res)(tanh)...
// 3-level z decomposition: z0 = z%d0, z1 = (z/d0)%d1, z2 = z/(d0*d1);
// per-operand offsets s0,s1,s2 (elements, may be negative).
// ---------------------------------------------------------------------------
struct GA {
  const f16* A; const f16* B;
  f16* Ch; float* Cf; const float* Res; const float* bias;
  long As0, As1, As2, Bs0, Bs1, Bs2, Cs0, Cs1, Cs2;
  int lda, ldb, ldc, K, d0, d1;
  float scale;
};

enum { FB_BIAS = 1, FB_RES = 2, FB_OUTF32 = 4, FB_OUTF16 = 8, FB_TANH = 16, FB_SCALE = 32 };

template <int BM, int BN, int WM, int WN, int FLAGS>
__global__ __launch_bounds__(256) void gemm_nt(GA a) {
  constexpr int MW = BM / WM;
  constexpr int MI = WM / 16, NI = WN / 16;
  constexpr int CA_ = (4 * BM) / 256;
  constexpr int CB_ = (4 * BN) / 256;

  const int lane = threadIdx.x & 63;
  const int w = threadIdx.x >> 6;
  const int wm = w % MW, wn = w / MW;

  const int z = blockIdx.z;
  const int z0 = z % a.d0;
  const int zt = z / a.d0;
  const int z1 = zt % a.d1, z2 = zt / a.d1;
  const f16* Ap = a.A + z0 * a.As0 + z1 * a.As1 + z2 * a.As2 + (long)blockIdx.x * BM * a.lda;
  const f16* Bp = a.B + z0 * a.Bs0 + z1 * a.Bs1 + z2 * a.Bs2 + (long)blockIdx.y * BN * a.ldb;

  __shared__ __attribute__((aligned(16))) f16 sA[BM * 32];
  __shared__ __attribute__((aligned(16))) f16 sB[BN * 32];

  floatx4 acc[MI][NI] = {};

  for (int k0 = 0; k0 < a.K; k0 += 32) {
    __syncthreads();
#pragma unroll
    for (int c = 0; c < CA_; ++c) {
      int s = (w * CA_ + c) * 64 + lane;
      int g = s / BM, r = s - g * BM;
      async16(Ap + (long)r * a.lda + (k0 + g * 8), &sA[s * 8]);
    }
#pragma unroll
    for (int c = 0; c < CB_; ++c) {
      int s = (w * CB_ + c) * 64 + lane;
      int g = s / BN, r = s - g * BN;
      async16(Bp + (long)r * a.ldb + (k0 + g * 8), &sB[s * 8]);
    }
    __syncthreads();

    hfrag af[MI], bfr[NI];
#pragma unroll
    for (int i = 0; i < MI; ++i)
      af[i] = *(const hfrag*)&sA[((lane >> 4) * BM + wm * WM + i * 16 + (lane & 15)) * 8];
#pragma unroll
    for (int j = 0; j < NI; ++j)
      bfr[j] = *(const hfrag*)&sB[((lane >> 4) * BN + wn * WN + j * 16 + (lane & 15)) * 8];
#pragma unroll
    for (int i = 0; i < MI; ++i)
#pragma unroll
      for (int j = 0; j < NI; ++j)
        acc[i][j] = __builtin_amdgcn_mfma_f32_16x16x32_f16(af[i], bfr[j], acc[i][j], 0, 0, 0);
  }

  const long zofsC = z0 * a.Cs0 + z1 * a.Cs1 + z2 * a.Cs2;
  const int r0 = (lane >> 4) * 4, c0 = lane & 15;
#pragma unroll
  for (int i = 0; i < MI; ++i) {
#pragma unroll
    for (int j = 0; j < NI; ++j) {
      int gc = blockIdx.y * BN + wn * WN + j * 16 + c0;
#pragma unroll
      for (int r = 0; r < 4; ++r) {
        long row = (long)blockIdx.x * BM + wm * WM + i * 16 + r0 + r;
        float v = acc[i][j][r];
        if constexpr ((FLAGS & FB_SCALE) != 0) v *= a.scale;
        if constexpr ((FLAGS & FB_BIAS) != 0) v += a.bias[gc];
        long idx = row * a.ldc + gc + zofsC;
        if constexpr ((FLAGS & FB_RES) != 0) v += a.Res[idx];
        if constexpr ((FLAGS & FB_OUTF32) != 0) a.Cf[idx] = v;
        if constexpr ((FLAGS & FB_TANH) != 0) v = fast_tanh(v);
        if constexpr ((FLAGS & FB_OUTF16) != 0) a.Ch[idx] = (f16)v;
      }
    }
  }
}

// ---------------------------------------------------------------------------
// Fused S-GEMM + exact softmax. Block: 32 q-rows x all 512 keys, K=64.
// grid (16 qtiles, 128 z), z = pair*64 + b*8 + h. Writes P (f16) row-major.
// ---------------------------------------------------------------------------
__global__ __launch_bounds__(256) void k_attn_s(const f16* __restrict__ qkv, f16* __restrict__ P) {
  const int lane = threadIdx.x & 63;
  const int w = threadIdx.x >> 6;  // wave = column group of 128 keys
  const int qt = blockIdx.x;
  const int z = blockIdx.y;
  const int pair = z >> 6, b = (z >> 3) & 7, h = z & 7;
  const f16* Qb = qkv + (long)pair * 6291456 + (long)b * 786432 + h * 64;
  const f16* Kb = Qb + 512;

  __shared__ __attribute__((aligned(16))) f16 sA[8 * 32 * 8];   // 4 KB
  __shared__ __attribute__((aligned(16))) f16 sB[8 * 512 * 8];  // 64 KB
  __shared__ float red[4][32];

  {
    int s = w * 64 + lane;
    int g = s >> 5, r = s & 31;
    async16(Qb + (long)(qt * 32 + r) * 1536 + g * 8, &sA[s * 8]);
  }
#pragma unroll
  for (int c = 0; c < 16; ++c) {
    int s = (w * 16 + c) * 64 + lane;
    int g = s >> 9, r = s & 511;
    async16(Kb + (long)r * 1536 + g * 8, &sB[s * 8]);
  }
  __syncthreads();

  const int q16 = lane & 15, quad = lane >> 4;
  floatx4 acc[2][8] = {};
#pragma unroll
  for (int kk = 0; kk < 2; ++kk) {
    hfrag af[2], bf[8];
#pragma unroll
    for (int i = 0; i < 2; ++i)
      af[i] = *(const hfrag*)&sA[((kk * 4 + quad) * 32 + i * 16 + q16) * 8];
#pragma unroll
    for (int j = 0; j < 8; ++j)
      bf[j] = *(const hfrag*)&sB[((kk * 4 + quad) * 512 + w * 128 + j * 16 + q16) * 8];
#pragma unroll
    for (int i = 0; i < 2; ++i)
#pragma unroll
      for (int j = 0; j < 8; ++j)
        acc[i][j] = __builtin_amdgcn_mfma_f32_16x16x32_f16(af[i], bf[j], acc[i][j], 0, 0, 0);
  }
#pragma unroll
  for (int i = 0; i < 2; ++i)
#pragma unroll
    for (int j = 0; j < 8; ++j)
#pragma unroll
      for (int r = 0; r < 4; ++r) acc[i][j][r] *= 0.125f;

  float mrow[2][4], lrow[2][4];
#pragma unroll
  for (int i = 0; i < 2; ++i)
#pragma unroll
    for (int r = 0; r < 4; ++r) {
      float mx = acc[i][0][r];
#pragma unroll
      for (int j = 1; j < 8; ++j) mx = fmaxf(mx, acc[i][j][r]);
#pragma unroll
      for (int o = 1; o < 16; o <<= 1) mx = fmaxf(mx, __shfl_xor(mx, o));
      mrow[i][r] = mx;
    }
  if (q16 == 0) {
#pragma unroll
    for (int i = 0; i < 2; ++i)
#pragma unroll
      for (int r = 0; r < 4; ++r) red[w][i * 16 + quad * 4 + r] = mrow[i][r];
  }
  __syncthreads();
#pragma unroll
  for (int i = 0; i < 2; ++i)
#pragma unroll
    for (int r = 0; r < 4; ++r) {
      int row = i * 16 + quad * 4 + r;
      mrow[i][r] = fmaxf(fmaxf(red[0][row], red[1][row]), fmaxf(red[2][row], red[3][row]));
    }
  __syncthreads();
#pragma unroll
  for (int i = 0; i < 2; ++i)
#pragma unroll
    for (int r = 0; r < 4; ++r) {
      float s = 0.f;
#pragma unroll
      for (int j = 0; j < 8; ++j) {
        float e = __expf(acc[i][j][r] - mrow[i][r]);
        acc[i][j][r] = e;
        s += e;
      }
#pragma unroll
      for (int o = 1; o < 16; o <<= 1) s += __shfl_xor(s, o);
      lrow[i][r] = s;
    }
  if (q16 == 0) {
#pragma unroll
    for (int i = 0; i < 2; ++i)
#pragma unroll
      for (int r = 0; r < 4; ++r) red[w][i * 16 + quad * 4 + r] = lrow[i][r];
  }
  __syncthreads();
  f16* Pz = P + (long)z * 262144 + (long)qt * 32 * 512;
#pragma unroll
  for (int i = 0; i < 2; ++i)
#pragma unroll
    for (int r = 0; r < 4; ++r) {
      int row = i * 16 + quad * 4 + r;
      float l = red[0][row] + red[1][row] + red[2][row] + red[3][row];
      float inv = 1.0f / l;
#pragma unroll
      for (int j = 0; j < 8; ++j)
        Pz[(long)row * 512 + w * 128 + j * 16 + q16] = (f16)(acc[i][j][r] * inv);
    }
}

// ------------------------------ aux kernels --------------------------------

struct CvtSeg { const float* s; f16* d; int n; };
struct Cvt5 { CvtSeg seg[5]; };

DEVI void st4h(f16* d, float4 v) {
  f16x4 o; o[0] = (f16)v.x; o[1] = (f16)v.y; o[2] = (f16)v.z; o[3] = (f16)v.w;
  *(f16x4*)d = o;
}

__global__ void k_cvt5(Cvt5 a) {
  CvtSeg sg = a.seg[blockIdx.y];
  int i = (blockIdx.x * 256 + threadIdx.x) * 4;
  if (i < sg.n) st4h(sg.d + i, *(const float4*)(sg.s + i));
}

__global__ void k_cvt_x(const float* __restrict__ x1, const float* __restrict__ x2,
                        f16* __restrict__ dst) {
  long i = ((long)blockIdx.x * 256 + threadIdx.x) * 4;
  const float* s = blockIdx.y ? x2 : x1;
  f16* d = dst + (long)blockIdx.y * 4194304;
  st4h(d + i, *(const float4*)(s + i));
}

// Wbins[n][d][k] (f32, 512x256) -> O[n][k][d] (f16, 256x512)
__global__ void k_binsT(const float* __restrict__ W, f16* __restrict__ O) {
  __shared__ float t[32][33];
  int n = blockIdx.z;
  int k0 = blockIdx.x * 32, d0 = blockIdx.y * 32;
  int tx = threadIdx.x & 31, ty = threadIdx.x >> 5;
  const float* Wn = W + (long)n * 131072;
#pragma unroll
  for (int rr = 0; rr < 32; rr += 8)
    t[ty + rr][tx] = Wn[(long)(d0 + ty + rr) * 256 + k0 + tx];
  __syncthreads();
  f16* On = O + (long)n * 131072;
#pragma unroll
  for (int rr = 0; rr < 32; rr += 8)
    On[(long)(k0 + ty + rr) * 512 + d0 + tx] = (f16)t[tx][ty + rr];
}

// qkv v-slice -> vT[z][64][512], z = pair*64 + b*8 + h
__global__ void k_vtrans(const unsigned short* __restrict__ qkv, unsigned short* __restrict__ vT) {
  __shared__ unsigned short t[32][33];
  int z = blockIdx.z;
  int pair = z >> 6, b = (z >> 3) & 7, h = z & 7;
  int l0 = blockIdx.x * 32, d0 = blockIdx.y * 32;
  int tx = threadIdx.x & 31, ty = threadIdx.x >> 5;
  const unsigned short* src = qkv + (long)pair * 6291456 + (long)b * 786432 + 1024 + h * 64;
#pragma unroll
  for (int rr = 0; rr < 32; rr += 8)
    t[ty + rr][tx] = src[(long)(l0 + ty + rr) * 1536 + d0 + tx];
  __syncthreads();
  unsigned short* dst = vT + (long)z * 32768;
#pragma unroll
  for (int rr = 0; rr < 32; rr += 8)
    dst[(long)(d0 + ty + rr) * 512 + l0 + tx] = t[tx][ty + rr];
}

// Bin smoothing: raw f16 cm -> smoothed f32 (d_out), fused cm1 + rowpre.
// grid (512 = i, 8 = b); thread owns (i, j=2t..2t+1) for all 25 bins.
__global__ void k_smooth(const f16* __restrict__ raw, float* __restrict__ out_cm,
                         const float* __restrict__ sm, const float* __restrict__ agg,
                         float* __restrict__ rp) {
  int i = blockIdx.x, b = blockIdx.y;
  int t = threadIdx.x;
  int j = t * 2;
  float sw[5];
#pragma unroll
  for (int k = 0; k < 5; ++k) sw[k] = sm[k];
  float r0[25], r1[25];
  const f16* base = raw + (long)b * 6553600 + (long)i * 512 + j;
#pragma unroll
  for (int n = 0; n < 25; ++n) {
    f16x2 v = *(const f16x2*)(base + (long)n * 262144);
    r0[n] = (float)v[0]; r1[n] = (float)v[1];
  }
  float* ob = out_cm + (long)b * 6553600 + (long)i * 512 + j;
  float a0 = 0.f, a1 = 0.f;
#pragma unroll
  for (int n = 0; n < 25; ++n) {
    float t0 = 0.f, t1 = 0.f;
#pragma unroll
    for (int k = 0; k < 5; ++k) {
      int mi = n + k - 2;
      if (mi >= 0 && mi < 25) { t0 += sw[k] * r0[mi]; t1 += sw[k] * r1[mi]; }
    }
    float2 o2; o2.x = t0; o2.y = t1;
    *(float2*)(ob + (long)n * 262144) = o2;
    float ag = agg[n];
    a0 += ag * t0; a1 += ag * t1;
  }
  float c0 = fast_tanh(a0), c1 = fast_tanh(a1);

  __shared__ float red[256];
  __shared__ float ef[10], el[10];
  red[t] = c0 + c1;
  if (t < 5) { ef[2 * t] = c0; ef[2 * t + 1] = c1; }
  if (t >= 251) { el[2 * t - 502] = c0; el[2 * t - 501] = c1; }
  __syncthreads();
  for (int s = 128; s > 0; s >>= 1) {
    if (t < s) red[t] += red[t + s];
    __syncthreads();
  }
  if (t == 0) {
    float total = red[0];
    float suf[10]; suf[0] = 0.f;
#pragma unroll
    for (int s2 = 1; s2 <= 9; ++s2) suf[s2] = suf[s2 - 1] + el[10 - s2];
    float pre = 0.f;
    float* rpo = rp + ((long)b * 512 + i) * 10;
#pragma unroll
    for (int jj = 0; jj < 10; ++jj) {
      rpo[jj] = total - pre - suf[9 - jj];
      pre += ef[jj];
    }
  }
}

// wsum[b][i][j] = sum_{a=i}^{i+502} rp[b][a][j]; block per (b,j).
__global__ void k_wsum(const float* __restrict__ rp, float* __restrict__ wst) {
  int b = blockIdx.x / 10, j = blockIdx.x % 10;
  int t = threadIdx.x;
  const float* base = rp + (long)b * 5120 + j;
  float v = base[(long)t * 10] + base[(long)(t + 256) * 10];
  __shared__ float sh[256];
  sh[t] = v;
  __syncthreads();
  for (int s = 128; s > 0; s >>= 1) {
    if (t < s) sh[t] += sh[t + s];
    __syncthreads();
  }
  if (t == 0) {
    float total = sh[0];
    float suf[10]; suf[0] = 0.f;
    for (int s2 = 1; s2 <= 9; ++s2) suf[s2] = suf[s2 - 1] + base[(long)(512 - s2) * 10];
    float pre = 0.f;
    for (int i2 = 0; i2 < 10; ++i2) {
      wst[b * 100 + i2 * 10 + j] = total - pre - suf[9 - i2];
      pre += base[(long)i2 * 10];
    }
  }
}

__global__ void k_pp(const float* __restrict__ wst, const float* __restrict__ Lmat,
                     const float* __restrict__ biasp, float* __restrict__ out) {
  int b = threadIdx.x;
  if (b < 8) {
    float acc = biasp[0];
    for (int p = 0; p < 100; ++p) acc += fast_tanh(wst[b * 100 + p]) * Lmat[p];
    out[b] = 1.0f / (1.0f + __expf(-acc));
  }
}

// ------------------------------ host launcher ------------------------------

extern "C" void kernel_launch(void* const* d_in, const int* in_sizes, int n_in,
                              void* d_out, int out_size, void* d_ws, size_t ws_size,
                              hipStream_t stream) {
  (void)in_sizes; (void)n_in; (void)out_size; (void)ws_size;
  const float* x1 = (const float*)d_in[0];
  const float* x2 = (const float*)d_in[1];
  const float* proj_w = (const float*)d_in[2];
  const float* proj_b = (const float*)d_in[3];
  const float* mha_in_w = (const float*)d_in[4];
  const float* mha_in_b = (const float*)d_in[5];
  const float* mha_out_w = (const float*)d_in[6];
  const float* mha_out_b = (const float*)d_in[7];
  const float* ca_in_w = (const float*)d_in[8];
  const float* ca_in_b = (const float*)d_in[9];
  const float* ca_out_w = (const float*)d_in[10];
  const float* ca_out_b = (const float*)d_in[11];
  const float* Wbins = (const float*)d_in[12];
  const float* agg = (const float*)d_in[13];
  const float* Lmat = (const float*)d_in[14];
  const float* biasp = (const float*)d_in[15];
  const float* smooth = (const float*)d_in[16];

  float* out_cm = (float*)d_out;
  float* out_pp = out_cm + 52428800L;

  char* wsp = (char*)d_ws;
  size_t o = 0;
  auto take = [&](size_t bytes) {
    void* p = wsp + o;
    o += (bytes + 255) & ~(size_t)255;
    return p;
  };
  f16* wbProj = (f16*)take(1048576);
  f16* wbMhaIn = (f16*)take(1572864);
  f16* wbMhaOut = (f16*)take(524288);
  f16* wbCaIn = (f16*)take(1572864);
  f16* wbCaOut = (f16*)take(524288);
  f16* wbBins = (f16*)take(6553600);
  f16* xin = (f16*)take(16777216);   // [2][4096][1024]
  float* xf = (float*)take(16777216); // [2][4096][512]
  f16* xb = (f16*)take(8388608);      // [2][4096][512]
  float* rp = (float*)take(163840);
  float* wst = (float*)take(3328);
  char* U = wsp + o;
  f16* qkv = (f16*)(U);                 // [2][4096][1536] = 24 MB
  f16* vT = (f16*)(U + 25165824);       // [128][64][512] = 8 MB
  f16* ao = (f16*)(U + 33554432);       // [2][4096][512] = 8 MB
  f16* P = (f16*)(U + 41943040);        // [128][512][512] = 64 MB
  f16* h = (f16*)(U + 109051904);       // [2][8][25][512][256] = 100 MB
  f16* cmraw = (f16*)(U);               // overlays qkv..P (dead by then), 105 MB

  // --- conversions ---
  {
    Cvt5 c;
    c.seg[0] = {proj_w, wbProj, 524288};
    c.seg[1] = {mha_in_w, wbMhaIn, 786432};
    c.seg[2] = {mha_out_w, wbMhaOut, 262144};
    c.seg[3] = {ca_in_w, wbCaIn, 786432};
    c.seg[4] = {ca_out_w, wbCaOut, 262144};
    k_cvt5<<<dim3(768, 5), 256, 0, stream>>>(c);
  }
  k_cvt_x<<<dim3(4096, 2), 256, 0, stream>>>(x1, x2, xin);
  k_binsT<<<dim3(8, 16, 25), 256, 0, stream>>>(Wbins, wbBins);

  // --- projection (z = pair) ---
  {
    GA g{}; g.A = xin; g.lda = 1024; g.As1 = 4194304;
    g.B = wbProj; g.ldb = 1024; g.bias = proj_b;
    g.Cf = xf; g.Ch = xb; g.ldc = 512; g.Cs1 = 2097152;
    g.K = 1024; g.d0 = 1; g.d1 = 1024;
    gemm_nt<128, 64, 64, 32, FB_BIAS | FB_OUTF32 | FB_OUTF16>
        <<<dim3(32, 8, 2), 256, 0, stream>>>(g);
  }

  auto attention = [&](const f16* w_out, const float* b_out, bool writeF32) {
    k_vtrans<<<dim3(16, 2, 128), 256, 0, stream>>>((const unsigned short*)qkv, (unsigned short*)vT);
    k_attn_s<<<dim3(16, 128), 256, 0, stream>>>(qkv, P);
    {  // PV: ao[pair][b][l][h*64+d] = P @ vT^T
      GA g{}; g.A = P; g.lda = 512; g.As0 = 262144; g.As1 = 2097152; g.As2 = 16777216;
      g.B = vT; g.ldb = 512; g.Bs0 = 32768; g.Bs1 = 262144; g.Bs2 = 2097152;
      g.Ch = ao; g.ldc = 512; g.Cs0 = 64; g.Cs1 = 262144; g.Cs2 = 2097152;
      g.K = 512; g.d0 = 8; g.d1 = 8;
      gemm_nt<128, 64, 64, 32, FB_OUTF16><<<dim3(4, 1, 128), 256, 0, stream>>>(g);
    }
    {  // out-proj + residual + tanh (z = pair)
      GA g{}; g.A = ao; g.lda = 512; g.As1 = 2097152;
      g.B = w_out; g.ldb = 512; g.bias = b_out;
      g.Res = xf; g.Cf = xf; g.Ch = xb; g.ldc = 512; g.Cs1 = 2097152;
      g.K = 512; g.d0 = 1; g.d1 = 1024;
      if (writeF32)
        gemm_nt<128, 64, 64, 32, FB_BIAS | FB_RES | FB_OUTF32 | FB_OUTF16 | FB_TANH>
            <<<dim3(32, 8, 2), 256, 0, stream>>>(g);
      else
        gemm_nt<128, 64, 64, 32, FB_BIAS | FB_RES | FB_OUTF16 | FB_TANH>
            <<<dim3(32, 8, 2), 256, 0, stream>>>(g);
    }
  };

  // --- self-MHA (both pairs batched) ---
  {
    GA g{}; g.A = xb; g.lda = 512; g.As1 = 2097152;
    g.B = wbMhaIn; g.ldb = 512; g.bias = mha_in_b;
    g.Ch = qkv; g.ldc = 1536; g.Cs1 = 6291456;
    g.K = 512; g.d0 = 1; g.d1 = 1024;
    gemm_nt<128, 64, 64, 32, FB_BIAS | FB_OUTF16><<<dim3(32, 24, 2), 256, 0, stream>>>(g);
  }
  attention(wbMhaOut, mha_out_b, true);

  // --- cross-attention qkv: q from own side, kv from the other ---
  {
    GA g{}; g.A = xb; g.lda = 512; g.As1 = 2097152;
    g.B = wbCaIn; g.ldb = 512; g.bias = ca_in_b;
    g.Ch = qkv; g.ldc = 1536; g.Cs1 = 6291456;
    g.K = 512; g.d0 = 1; g.d1 = 1024;
    gemm_nt<128, 64, 64, 32, FB_BIAS | FB_OUTF16><<<dim3(32, 8, 2), 256, 0, stream>>>(g);
  }
  {
    GA g{}; g.A = xb + 2097152; g.lda = 512; g.As1 = -2097152;  // z=0 -> xb2, z=1 -> xb1
    g.B = wbCaIn + 262144; g.ldb = 512; g.bias = ca_in_b + 512;
    g.Ch = qkv + 512; g.ldc = 1536; g.Cs1 = 6291456;
    g.K = 512; g.d0 = 1; g.d1 = 1024;
    gemm_nt<128, 64, 64, 32, FB_BIAS | FB_OUTF16><<<dim3(32, 16, 2), 256, 0, stream>>>(g);
  }
  attention(wbCaOut, ca_out_b, false);

  // --- h GEMMs, both sides in one launch: z = s*200 + b*25 + n ---
  {
    GA g{}; g.A = xb; g.lda = 512; g.As0 = 0; g.As1 = 262144; g.As2 = 2097152;
    g.B = wbBins; g.ldb = 512; g.Bs0 = 131072;
    g.Ch = h; g.ldc = 256; g.Cs0 = 131072; g.Cs1 = 3276800; g.Cs2 = 26214400;
    g.K = 512; g.d0 = 25; g.d1 = 8;
    gemm_nt<128, 128, 64, 64, FB_OUTF16 | FB_TANH><<<dim3(4, 2, 400), 256, 0, stream>>>(g);
  }

  // --- cm_raw (f16, ws) = h1 @ h2^T : z = b*25 + n ---
  {
    GA g{}; g.A = h; g.lda = 256; g.As0 = 131072; g.As1 = 3276800;
    g.B = h + 26214400; g.ldb = 256; g.Bs0 = 131072; g.Bs1 = 3276800;
    g.Ch = cmraw; g.ldc = 512; g.Cs0 = 262144; g.Cs1 = 6553600;
    g.K = 256; g.d0 = 25; g.d1 = 8;
    gemm_nt<128, 128, 64, 64, FB_OUTF16><<<dim3(4, 4, 200), 256, 0, stream>>>(g);
  }

  // --- smoothing + cm1 + rowpre fused ---
  k_smooth<<<dim3(512, 8), 256, 0, stream>>>(cmraw, out_cm, smooth, agg, rp);

  // --- box sums + logistic head ---
  k_wsum<<<80, 256, 0, stream>>>(rp, wst);
  k_pp<<<1, 64, 0, stream>>>(wst, Lmat, biasp, out_pp);
}